// Round 18
// baseline (156.095 us; speedup 1.0000x reference)
//
#include <hip/hip_runtime.h>

#define NN 768
#define HH 128
#define TJ 64
#define NT (NN / TJ)          // 12 j-tiles
#define THREADS 512

typedef __bf16 bf16x8 __attribute__((ext_vector_type(8)));
typedef float f32x4 __attribute__((ext_vector_type(4)));

union U8 { __bf16 h[8]; unsigned short s[8]; uint4 u; bf16x8 b; };
union U4 { __bf16 h[4]; uint2 u2; };

__device__ __forceinline__ float fast_sig(float x) {
    return __builtin_amdgcn_rcpf(1.0f + __expf(-x));
}
__device__ __forceinline__ float fast_silu(float x) { return x * fast_sig(x); }

__device__ __forceinline__ f32x4 MFMA(bf16x8 a, bf16x8 b, f32x4 c) {
    return __builtin_amdgcn_mfma_f32_16x16x32_bf16(a, b, c, 0, 0, 0);
}

__device__ __forceinline__ bf16x8 ldfrag(const unsigned short* buf, int off) {
    U8 r;
    r.u = *(const uint4*)((const char*)buf + off);
    return r.b;
}

// ---------------- K1: per-node projections AiP/AjP ----------------
__global__ void precompute_proj(const float* __restrict__ nf,
                                const float* __restrict__ cons,
                                const float* __restrict__ memb,
                                const float* __restrict__ cata,
                                const float* __restrict__ eW1,
                                const float* __restrict__ eb1,
                                float* __restrict__ AiP,
                                float* __restrict__ AjP) {
    __shared__ float row[HH];
    int i = blockIdx.x;
    int h = threadIdx.x;
    row[h] = nf[i * HH + h];
    __syncthreads();
    float ci = cons[i], mi = memb[i], ti = cata[i];
    float ai = eb1[h] + ci * eW1[257 * HH + h] + mi * eW1[259 * HH + h];
    float aj = ci * eW1[258 * HH + h] + ti * eW1[260 * HH + h];
    for (int k = 0; k < HH; ++k) {
        float x = row[k];
        ai = fmaf(x, eW1[k * HH + h], ai);
        aj = fmaf(x, eW1[(HH + k) * HH + h], aj);
    }
    AiP[i * HH + h] = ai;
    AjP[i * HH + h] = aj;
}

// ---------------- K2: main per-row MFMA kernel (transposed GEMMs) --------
// Round-17 structure (proven 106 us) with ONE change pair:
//  - dirx/diry/dirz LDS arrays dropped (-9.2 KB -> 49.5 KB LDS);
//    direction recomputed from pos ONLY in the vector-message step
//    (8 lanes/wave, 12x) — BUILD still reads staged distL/pmvL.
//  - __launch_bounds__(512,6): measured r17 allocation = 64 VGPR <= 85
//    cap, so no spill expected; 3 blocks/CU, all 768 blocks resident.
__global__ void __launch_bounds__(THREADS, 6)
main_kernel(const float* __restrict__ nf, const float* __restrict__ vf,
            const float* __restrict__ pos, const int* __restrict__ pm,
            const float* __restrict__ eW1, const float* __restrict__ eW2,
            const float* __restrict__ eb2,
            const float* __restrict__ sW1, const float* __restrict__ sb1,
            const float* __restrict__ sW2, const float* __restrict__ sb2,
            const float* __restrict__ gW1, const float* __restrict__ gb1,
            const float* __restrict__ gW2, const float* __restrict__ gb2,
            const float* __restrict__ ln_g, const float* __restrict__ ln_b,
            const float* __restrict__ AiP, const float* __restrict__ AjP,
            float* __restrict__ out_scalar, float* __restrict__ out_vec,
            float* __restrict__ out_ew) {
    // ---- LDS (~49.5 KB -> 3 blocks/CU) ----
    __shared__ __align__(16) unsigned short S1[TJ * HH];   // 16 KB, swizzled
    __shared__ __align__(16) unsigned short EH[TJ * HH];   // 16 KB, swizzled
    __shared__ float distL[NN];
    __shared__ float pmvL[NN];
    __shared__ __align__(16) float baseI[HH];
    __shared__ __align__(16) float wdR[HH];
    __shared__ __align__(16) float wpR[HH];
    __shared__ __align__(16) float ebL[HH];
    __shared__ __align__(16) float gbL[HH];
    __shared__ __align__(16) float g2L[HH];
    __shared__ __align__(16) float ewpart[TJ][12];   // transposed, rows 48B
    __shared__ float ewG[TJ];
    __shared__ float vpart[TJ][9];
    __shared__ __align__(16) float mpart[HH];
    __shared__ float vbuf[TJ * 3];
    __shared__ float suin[2 * HH];
    __shared__ float hbuf[HH];
    __shared__ float red2[4];

    const int t = threadIdx.x;
    const int i = blockIdx.x;

    // row-i position kept in registers (vector-message dir recompute)
    const float pxi = pos[i * 3 + 0];
    const float pyi = pos[i * 3 + 1];
    const float pzi = pos[i * 3 + 2];

    // ---- geometry + row staging (once per block) ----
    {
        for (int j = t; j < NN; j += THREADS) {
            float rx = pxi - pos[j * 3 + 0];
            float ry = pyi - pos[j * 3 + 1];
            float rz = pzi - pos[j * 3 + 2];
            float d = sqrtf(rx * rx + ry * ry + rz * rz);
            distL[j] = fmaxf(d, 1e-8f);
            pmvL[j] = (pm[i * NN + j] != 0) ? 1.0f : 0.0f;
        }
        if (t < HH) {
            baseI[t] = AiP[i * HH + t];
            wdR[t] = eW1[256 * HH + t];
            wpR[t] = eW1[261 * HH + t];
            ebL[t] = eb2[t];
            gbL[t] = gb1[t];
            g2L[t] = gW2[t];
        }
    }

    // ---- wave / lane decomposition ----
    const int w = t >> 6, l = t & 63;
    const int lr = l & 15;               // j within n-tile / weight col (h)
    const int lg = l >> 4;               // k-group / h-quad group
    const int colxor = lr << 4;          // full 16-slot swizzle
    const int aoff0 = lr * 256 + ((  0 + lg * 16) ^ colxor);
    const int aoff1 = lr * 256 + (( 64 + lg * 16) ^ colxor);
    const int aoff2 = lr * 256 + ((128 + lg * 16) ^ colxor);
    const int aoff3 = lr * 256 + ((192 + lg * 16) ^ colxor);
    const int ewr0 = lr * 256 + ((w * 32 + lg * 8) ^ colxor);
    const int hq = w * 16 + lg * 4;      // this lane's 4 h-rows base

    // ---- A-fragments (transposed weights), block-invariant, remat-proof ----
    auto loadA = [&](const float* __restrict__ W, int kc) -> bf16x8 {
        U8 tmp;
        int col = w * 16 + lr;
#pragma unroll
        for (int e = 0; e < 8; ++e)
            tmp.h[e] = (__bf16)W[(kc * 32 + lg * 8 + e) * HH + col];
        asm volatile("" : "+v"(tmp.u.x), "+v"(tmp.u.y),
                          "+v"(tmp.u.z), "+v"(tmp.u.w));
        return tmp.b;
    };
    const bf16x8 Wf0 = loadA(eW2, 0), Wf1 = loadA(eW2, 1),
                 Wf2 = loadA(eW2, 2), Wf3 = loadA(eW2, 3);
    const bf16x8 Gf0 = loadA(gW1, 0), Gf1 = loadA(gW1, 1),
                 Gf2 = loadA(gW1, 2), Gf3 = loadA(gW1, 3);

    const float gb2s = gb2[0];

    // ---- S1-build mapping (rows jj_s and jj_s+32) ----
    const int jj_s = t >> 4;                 // 0..31
    const int h8 = (t & 15) * 8;             // 8-col slice
    const int s1woff = jj_s * 256 + (((t & 15) * 16) ^ ((jj_s & 15) << 4));

    float macc0 = 0.f, macc1 = 0.f, macc2 = 0.f, macc3 = 0.f;
    float vmx = 0.f, vmy = 0.f, vmz = 0.f;   // vector message (8 lanes/wave)

    __syncthreads();   // geometry / staged rows ready

    for (int jt = 0; jt < NT; ++jt) {
        const int j0 = jt * TJ;

        // ---- phase 1: build S1 tile (2 rows/thread), bf16, swizzled ----
        {
            float4 a0 = *(const float4*)&baseI[h8];
            float4 a1 = *(const float4*)&baseI[h8 + 4];
            float4 w0 = *(const float4*)&wdR[h8];
            float4 w1 = *(const float4*)&wdR[h8 + 4];
            float4 p0 = *(const float4*)&wpR[h8];
            float4 p1 = *(const float4*)&wpR[h8 + 4];
#pragma unroll
            for (int rr = 0; rr < 2; ++rr) {
                int j = j0 + jj_s + rr * 32;
                float4 bj0 = *(const float4*)&AjP[j * HH + h8];
                float4 bj1 = *(const float4*)&AjP[j * HH + h8 + 4];
                float d = distL[j], pf = pmvL[j];
                U8 pk;
                pk.h[0] = (__bf16)fast_silu(a0.x + bj0.x + d * w0.x + pf * p0.x);
                pk.h[1] = (__bf16)fast_silu(a0.y + bj0.y + d * w0.y + pf * p0.y);
                pk.h[2] = (__bf16)fast_silu(a0.z + bj0.z + d * w0.z + pf * p0.z);
                pk.h[3] = (__bf16)fast_silu(a0.w + bj0.w + d * w0.w + pf * p0.w);
                pk.h[4] = (__bf16)fast_silu(a1.x + bj1.x + d * w1.x + pf * p1.x);
                pk.h[5] = (__bf16)fast_silu(a1.y + bj1.y + d * w1.y + pf * p1.y);
                pk.h[6] = (__bf16)fast_silu(a1.z + bj1.z + d * w1.z + pf * p1.z);
                pk.h[7] = (__bf16)fast_silu(a1.w + bj1.w + d * w1.w + pf * p1.w);
                *(uint4*)((char*)S1 + s1woff + rr * 8192) = pk.u;
            }
        }
        __syncthreads();   // b1: S1 ready; prev tile's vpart/ewG fenced

        // ---- deferred vector-message for previous tile (dir recomputed) ----
        if (jt > 0 && l < 8) {
            int jj = w * 8 + l;
            int jp = j0 - TJ + jj;
            float s = vpart[jj][0] + vpart[jj][1] + vpart[jj][2] + vpart[jj][3]
                    + vpart[jj][4] + vpart[jj][5] + vpart[jj][6] + vpart[jj][7];
            float vg = (s + gb2s) * ewG[jj];
            float rx = pxi - pos[jp * 3 + 0];
            float ry = pyi - pos[jp * 3 + 1];
            float rz = pzi - pos[jp * 3 + 2];
            float inv = 1.0f / distL[jp];
            vmx = fmaf(vg, rx * inv, vmx);
            vmy = fmaf(vg, ry * inv, vmy);
            vmz = fmaf(vg, rz * inv, vmz);
        }

        // ---- phase 2: GEMM1 -> EH^T, 4 n-tiles (j = lr,16+lr,32+lr,48+lr)
        f32x4 acc0, acc1, acc2, acc3;
        {
            float4 eb4 = *(const float4*)&ebL[hq];
            acc0[0] = eb4.x; acc0[1] = eb4.y; acc0[2] = eb4.z; acc0[3] = eb4.w;
            acc1 = acc0; acc2 = acc0; acc3 = acc0;
        }
        {
            bf16x8 b;
            b = ldfrag(S1, aoff0);         acc0 = MFMA(Wf0, b, acc0);
            b = ldfrag(S1, aoff0 + 4096);  acc1 = MFMA(Wf0, b, acc1);
            b = ldfrag(S1, aoff0 + 8192);  acc2 = MFMA(Wf0, b, acc2);
            b = ldfrag(S1, aoff0 + 12288); acc3 = MFMA(Wf0, b, acc3);
            b = ldfrag(S1, aoff1);         acc0 = MFMA(Wf1, b, acc0);
            b = ldfrag(S1, aoff1 + 4096);  acc1 = MFMA(Wf1, b, acc1);
            b = ldfrag(S1, aoff1 + 8192);  acc2 = MFMA(Wf1, b, acc2);
            b = ldfrag(S1, aoff1 + 12288); acc3 = MFMA(Wf1, b, acc3);
            b = ldfrag(S1, aoff2);         acc0 = MFMA(Wf2, b, acc0);
            b = ldfrag(S1, aoff2 + 4096);  acc1 = MFMA(Wf2, b, acc1);
            b = ldfrag(S1, aoff2 + 8192);  acc2 = MFMA(Wf2, b, acc2);
            b = ldfrag(S1, aoff2 + 12288); acc3 = MFMA(Wf2, b, acc3);
            b = ldfrag(S1, aoff3);         acc0 = MFMA(Wf3, b, acc0);
            b = ldfrag(S1, aoff3 + 4096);  acc1 = MFMA(Wf3, b, acc1);
            b = ldfrag(S1, aoff3 + 8192);  acc2 = MFMA(Wf3, b, acc2);
            b = ldfrag(S1, aoff3 + 12288); acc3 = MFMA(Wf3, b, acc3);
        }
        // ew partial row-sums: per-lane 4-h sum + 2 shfls, per n-tile
        // (transposed store: ewpart[j][w])
        {
            float s0 = acc0[0] + acc0[1] + acc0[2] + acc0[3];
            float s1 = acc1[0] + acc1[1] + acc1[2] + acc1[3];
            float s2 = acc2[0] + acc2[1] + acc2[2] + acc2[3];
            float s3 = acc3[0] + acc3[1] + acc3[2] + acc3[3];
            s0 += __shfl_xor(s0, 16); s0 += __shfl_xor(s0, 32);
            s1 += __shfl_xor(s1, 16); s1 += __shfl_xor(s1, 32);
            s2 += __shfl_xor(s2, 16); s2 += __shfl_xor(s2, 32);
            s3 += __shfl_xor(s3, 16); s3 += __shfl_xor(s3, 32);
            if (l < 16) {
                ewpart[l][w]      = s0;
                ewpart[16 + l][w] = s1;
                ewpart[32 + l][w] = s2;
                ewpart[48 + l][w] = s3;
            }
        }
        // packed EH writes (4 h-contiguous bf16 per n-tile)
        {
            U4 p0, p1, p2, p3;
            p0.h[0] = (__bf16)acc0[0]; p0.h[1] = (__bf16)acc0[1];
            p0.h[2] = (__bf16)acc0[2]; p0.h[3] = (__bf16)acc0[3];
            p1.h[0] = (__bf16)acc1[0]; p1.h[1] = (__bf16)acc1[1];
            p1.h[2] = (__bf16)acc1[2]; p1.h[3] = (__bf16)acc1[3];
            p2.h[0] = (__bf16)acc2[0]; p2.h[1] = (__bf16)acc2[1];
            p2.h[2] = (__bf16)acc2[2]; p2.h[3] = (__bf16)acc2[3];
            p3.h[0] = (__bf16)acc3[0]; p3.h[1] = (__bf16)acc3[1];
            p3.h[2] = (__bf16)acc3[2]; p3.h[3] = (__bf16)acc3[3];
            *(uint2*)((char*)EH + ewr0)          = p0.u2;
            *(uint2*)((char*)EH + ewr0 + 4096)   = p1.u2;
            *(uint2*)((char*)EH + ewr0 + 8192)   = p2.u2;
            *(uint2*)((char*)EH + ewr0 + 12288)  = p3.u2;
        }
        __syncthreads();   // b2: EH + ewpart ready

        // ---- phase 3a: redundant per-lane ew (vectorized float4 reads) ----
        float ew0, ew1, ew2, ew3;
        {
            float4 eA, eB;
            eA = *(const float4*)&ewpart[lr][0];
            eB = *(const float4*)&ewpart[lr][4];
            float s0 = (eA.x + eA.y + eA.z + eA.w) + (eB.x + eB.y + eB.z + eB.w);
            eA = *(const float4*)&ewpart[16 + lr][0];
            eB = *(const float4*)&ewpart[16 + lr][4];
            float s1 = (eA.x + eA.y + eA.z + eA.w) + (eB.x + eB.y + eB.z + eB.w);
            eA = *(const float4*)&ewpart[32 + lr][0];
            eB = *(const float4*)&ewpart[32 + lr][4];
            float s2 = (eA.x + eA.y + eA.z + eA.w) + (eB.x + eB.y + eB.z + eB.w);
            eA = *(const float4*)&ewpart[48 + lr][0];
            eB = *(const float4*)&ewpart[48 + lr][4];
            float s3 = (eA.x + eA.y + eA.z + eA.w) + (eB.x + eB.y + eB.z + eB.w);
            ew0 = fast_sig(s0 * (1.0f / HH)) * pmvL[j0 + lr];
            ew1 = fast_sig(s1 * (1.0f / HH)) * pmvL[j0 + 16 + lr];
            ew2 = fast_sig(s2 * (1.0f / HH)) * pmvL[j0 + 32 + lr];
            ew3 = fast_sig(s3 * (1.0f / HH)) * pmvL[j0 + 48 + lr];
        }
        // unique writers: wave 2*nt+(lr>>3), lane lg==0 writes j = nt*16+lr
        if (lg == 0 && (lr >> 3) == (w & 1)) {
            int nt = w >> 1;
            int jj = nt * 16 + lr;
            float ewv = (nt == 0) ? ew0 : (nt == 1) ? ew1 : (nt == 2) ? ew2 : ew3;
            out_ew[i * NN + j0 + jj] = ewv;
            ewG[jj] = ewv;
        }
        // ---- phase 3b: message acc FIRST (frees acc before GEMM2) ----
        macc0 += ew0 * acc0[0] + ew1 * acc1[0] + ew2 * acc2[0] + ew3 * acc3[0];
        macc1 += ew0 * acc0[1] + ew1 * acc1[1] + ew2 * acc2[1] + ew3 * acc3[1];
        macc2 += ew0 * acc0[2] + ew1 * acc1[2] + ew2 * acc2[2] + ew3 * acc3[2];
        macc3 += ew0 * acc0[3] + ew1 * acc1[3] + ew2 * acc2[3] + ew3 * acc3[3];

        // ---- phase 3c: GEMM2 -> G^T ----
        f32x4 g0, g1, g2, g3;
        {
            float4 gb4 = *(const float4*)&gbL[hq];
            g0[0] = gb4.x; g0[1] = gb4.y; g0[2] = gb4.z; g0[3] = gb4.w;
            g1 = g0; g2 = g0; g3 = g0;
        }
        {
            bf16x8 b;
            b = ldfrag(EH, aoff0);         g0 = MFMA(Gf0, b, g0);
            b = ldfrag(EH, aoff0 + 4096);  g1 = MFMA(Gf0, b, g1);
            b = ldfrag(EH, aoff0 + 8192);  g2 = MFMA(Gf0, b, g2);
            b = ldfrag(EH, aoff0 + 12288); g3 = MFMA(Gf0, b, g3);
            b = ldfrag(EH, aoff1);         g0 = MFMA(Gf1, b, g0);
            b = ldfrag(EH, aoff1 + 4096);  g1 = MFMA(Gf1, b, g1);
            b = ldfrag(EH, aoff1 + 8192);  g2 = MFMA(Gf1, b, g2);
            b = ldfrag(EH, aoff1 + 12288); g3 = MFMA(Gf1, b, g3);
            b = ldfrag(EH, aoff2);         g0 = MFMA(Gf2, b, g0);
            b = ldfrag(EH, aoff2 + 4096);  g1 = MFMA(Gf2, b, g1);
            b = ldfrag(EH, aoff2 + 8192);  g2 = MFMA(Gf2, b, g2);
            b = ldfrag(EH, aoff2 + 12288); g3 = MFMA(Gf2, b, g3);
            b = ldfrag(EH, aoff3);         g0 = MFMA(Gf3, b, g0);
            b = ldfrag(EH, aoff3 + 4096);  g1 = MFMA(Gf3, b, g1);
            b = ldfrag(EH, aoff3 + 8192);  g2 = MFMA(Gf3, b, g2);
            b = ldfrag(EH, aoff3 + 12288); g3 = MFMA(Gf3, b, g3);
        }
        // gate partials: per-lane silu-dot + 2 shfls, per n-tile
        {
            float4 g2v = *(const float4*)&g2L[hq];
            float v0 = fast_silu(g0[0]) * g2v.x + fast_silu(g0[1]) * g2v.y
                     + fast_silu(g0[2]) * g2v.z + fast_silu(g0[3]) * g2v.w;
            float v1 = fast_silu(g1[0]) * g2v.x + fast_silu(g1[1]) * g2v.y
                     + fast_silu(g1[2]) * g2v.z + fast_silu(g1[3]) * g2v.w;
            float v2 = fast_silu(g2[0]) * g2v.x + fast_silu(g2[1]) * g2v.y
                     + fast_silu(g2[2]) * g2v.z + fast_silu(g2[3]) * g2v.w;
            float v3 = fast_silu(g3[0]) * g2v.x + fast_silu(g3[1]) * g2v.y
                     + fast_silu(g3[2]) * g2v.z + fast_silu(g3[3]) * g2v.w;
            v0 += __shfl_xor(v0, 16); v0 += __shfl_xor(v0, 32);
            v1 += __shfl_xor(v1, 16); v1 += __shfl_xor(v1, 32);
            v2 += __shfl_xor(v2, 16); v2 += __shfl_xor(v2, 32);
            v3 += __shfl_xor(v3, 16); v3 += __shfl_xor(v3, 32);
            if (l < 16) {
                vpart[l][w]      = v0;
                vpart[16 + l][w] = v1;
                vpart[32 + l][w] = v2;
                vpart[48 + l][w] = v3;
            }
        }
        // (no 3rd barrier: vpart/ewG consumed next tile after b1)
    }

    // ---- final deferred vector-message (last tile, dir recomputed) ----
    __syncthreads();
    if (l < 8) {
        int jj = w * 8 + l;
        int jp = (NT - 1) * TJ + jj;
        float s = vpart[jj][0] + vpart[jj][1] + vpart[jj][2] + vpart[jj][3]
                + vpart[jj][4] + vpart[jj][5] + vpart[jj][6] + vpart[jj][7];
        float vg = (s + gb2s) * ewG[jj];
        float rx = pxi - pos[jp * 3 + 0];
        float ry = pyi - pos[jp * 3 + 1];
        float rz = pzi - pos[jp * 3 + 2];
        float inv = 1.0f / distL[jp];
        vmx = fmaf(vg, rx * inv, vmx);
        vmy = fmaf(vg, ry * inv, vmy);
        vmz = fmaf(vg, rz * inv, vmz);
        vbuf[jj * 3 + 0] = vmx;
        vbuf[jj * 3 + 1] = vmy;
        vbuf[jj * 3 + 2] = vmz;
    }
    // message finalize: reduce over the 16 j-lanes (once)
    macc0 += __shfl_xor(macc0, 1); macc0 += __shfl_xor(macc0, 2);
    macc0 += __shfl_xor(macc0, 4); macc0 += __shfl_xor(macc0, 8);
    macc1 += __shfl_xor(macc1, 1); macc1 += __shfl_xor(macc1, 2);
    macc1 += __shfl_xor(macc1, 4); macc1 += __shfl_xor(macc1, 8);
    macc2 += __shfl_xor(macc2, 1); macc2 += __shfl_xor(macc2, 2);
    macc2 += __shfl_xor(macc2, 4); macc2 += __shfl_xor(macc2, 8);
    macc3 += __shfl_xor(macc3, 1); macc3 += __shfl_xor(macc3, 2);
    macc3 += __shfl_xor(macc3, 4); macc3 += __shfl_xor(macc3, 8);
    if (lr == 0) {
        *(float4*)&mpart[hq] = make_float4(macc0, macc1, macc2, macc3);
    }
    __syncthreads();

    // ---- scalar-update MLP + LayerNorm (fp32, per row i) ----
    if (t < HH) {
        suin[t] = nf[i * HH + t];
        suin[HH + t] = mpart[t];
    }
    __syncthreads();
    if (t < HH) {
        float a = sb1[t];
        for (int k = 0; k < 2 * HH; ++k) a = fmaf(suin[k], sW1[k * HH + t], a);
        hbuf[t] = fast_silu(a);
    }
    __syncthreads();
    float x = 0.f, sx = 0.f, sq = 0.f;
    if (t < HH) {
        float a = sb2[t];
        for (int k = 0; k < HH; ++k) a = fmaf(hbuf[k], sW2[k * HH + t], a);
        x = nf[i * HH + t] + a;
        sx = x;
        sq = x * x;
    }
#pragma unroll
    for (int msk = 1; msk <= 32; msk <<= 1) {
        sx += __shfl_xor(sx, msk);
        sq += __shfl_xor(sq, msk);
    }
    if (t == 0)  { red2[0] = sx; red2[1] = sq; }
    if (t == 64) { red2[2] = sx; red2[3] = sq; }
    __syncthreads();
    if (t < HH) {
        float mean = (red2[0] + red2[2]) * (1.0f / HH);
        float var  = (red2[1] + red2[3]) * (1.0f / HH) - mean * mean;
        out_scalar[i * HH + t] =
            (x - mean) * rsqrtf(var + 1e-5f) * ln_g[t] + ln_b[t];
    }
    if (t < 3) {
        float v = vf[i * 3 + t];
        for (int g = 0; g < TJ; ++g) v += vbuf[g * 3 + t];
        out_vec[i * 3 + t] = v;
    }
}

extern "C" void kernel_launch(void* const* d_in, const int* in_sizes, int n_in,
                              void* d_out, int out_size, void* d_ws, size_t ws_size,
                              hipStream_t stream) {
    const float* nf   = (const float*)d_in[0];
    const float* vf   = (const float*)d_in[1];
    const float* pos  = (const float*)d_in[2];
    const int*   pm   = (const int*)d_in[3];
    const float* cons = (const float*)d_in[4];
    const float* memb = (const float*)d_in[5];
    const float* cata = (const float*)d_in[6];
    const float* eW1  = (const float*)d_in[7];
    const float* eb1  = (const float*)d_in[8];
    const float* eW2  = (const float*)d_in[9];
    const float* eb2  = (const float*)d_in[10];
    const float* sW1  = (const float*)d_in[11];
    const float* sb1  = (const float*)d_in[12];
    const float* sW2  = (const float*)d_in[13];
    const float* sb2  = (const float*)d_in[14];
    const float* gW1  = (const float*)d_in[15];
    const float* gb1  = (const float*)d_in[16];
    const float* gW2  = (const float*)d_in[17];
    const float* gb2  = (const float*)d_in[18];
    const float* lng  = (const float*)d_in[19];
    const float* lnb  = (const float*)d_in[20];

    float* out = (float*)d_out;
    float* out_scalar = out;                     // [768*128]
    float* out_vec    = out + NN * HH;           // [768*3]
    float* out_ew     = out + NN * HH + NN * 3;  // [768*768]

    float* AiP = (float*)d_ws;
    float* AjP = AiP + NN * HH;

    precompute_proj<<<NN, HH, 0, stream>>>(nf, cons, memb, cata, eW1, eb1, AiP, AjP);

    main_kernel<<<NN, THREADS, 0, stream>>>(
        nf, vf, pos, pm, eW1, eW2, eb2, sW1, sb1, sW2, sb2, gW1, gb1, gW2, gb2,
        lng, lnb, AiP, AjP, out_scalar, out_vec, out_ew);
}

// Round 19
// 105.260 us; speedup vs baseline: 1.4830x; 1.4830x over previous
//
#include <hip/hip_runtime.h>

#define NN 768
#define HH 128
#define TJ 64
#define NTB 6                 // j-tiles per block (half row)
#define JB  (NTB * TJ)        // 384 j's per block
#define THREADS 512

typedef __bf16 bf16x8 __attribute__((ext_vector_type(8)));
typedef float f32x4 __attribute__((ext_vector_type(4)));

union U8 { __bf16 h[8]; unsigned short s[8]; uint4 u; bf16x8 b; };
union U4 { __bf16 h[4]; uint2 u2; };

__device__ __forceinline__ float fast_sig(float x) {
    return __builtin_amdgcn_rcpf(1.0f + __expf(-x));
}
__device__ __forceinline__ float fast_silu(float x) { return x * fast_sig(x); }

__device__ __forceinline__ f32x4 MFMA(bf16x8 a, bf16x8 b, f32x4 c) {
    return __builtin_amdgcn_mfma_f32_16x16x32_bf16(a, b, c, 0, 0, 0);
}

__device__ __forceinline__ bf16x8 ldfrag(const unsigned short* buf, int off) {
    U8 r;
    r.u = *(const uint4*)((const char*)buf + off);
    return r.b;
}

// ---------------- K1: per-node projections AiP/AjP ----------------
__global__ void precompute_proj(const float* __restrict__ nf,
                                const float* __restrict__ cons,
                                const float* __restrict__ memb,
                                const float* __restrict__ cata,
                                const float* __restrict__ eW1,
                                const float* __restrict__ eb1,
                                float* __restrict__ AiP,
                                float* __restrict__ AjP) {
    __shared__ float row[HH];
    int i = blockIdx.x;
    int h = threadIdx.x;
    row[h] = nf[i * HH + h];
    __syncthreads();
    float ci = cons[i], mi = memb[i], ti = cata[i];
    float ai = eb1[h] + ci * eW1[257 * HH + h] + mi * eW1[259 * HH + h];
    float aj = ci * eW1[258 * HH + h] + ti * eW1[260 * HH + h];
    for (int k = 0; k < HH; ++k) {
        float x = row[k];
        ai = fmaf(x, eW1[k * HH + h], ai);
        aj = fmaf(x, eW1[(HH + k) * HH + h], aj);
    }
    AiP[i * HH + h] = ai;
    AjP[i * HH + h] = aj;
}

// ---------------- K2: main kernel — HALF ROW per block ----------------
// Round-17 structure (proven 106 us), grid = 1536: block b handles row
// i = b>>1, j-half z = b&1 (6 of 12 j-tiles). 1536 half-length blocks at
// 2 blocks/CU pack into exactly 3 full dispatch rounds (vs 1.5 rounds of
// full-length blocks executed as ~2 -> removes the half-idle tail round).
// Partial message/vector-message written to d_ws (unique writer/block);
// K3 combines + does the scalar MLP / LayerNorm epilogue.
__global__ void __launch_bounds__(THREADS, 4)
main_kernel(const float* __restrict__ pos, const int* __restrict__ pm,
            const float* __restrict__ eW1, const float* __restrict__ eW2,
            const float* __restrict__ eb2,
            const float* __restrict__ gW1, const float* __restrict__ gb1,
            const float* __restrict__ gW2, const float* __restrict__ gb2,
            const float* __restrict__ AiP, const float* __restrict__ AjP,
            float* __restrict__ mpartW, float* __restrict__ vmW,
            float* __restrict__ out_ew) {
    // ---- LDS (~46 KB) ----
    __shared__ __align__(16) unsigned short S1[TJ * HH];   // 16 KB, swizzled
    __shared__ __align__(16) unsigned short EH[TJ * HH];   // 16 KB, swizzled
    __shared__ float distL[JB];
    __shared__ float pmvL[JB];
    __shared__ __align__(16) float baseI[HH];
    __shared__ __align__(16) float wdR[HH];
    __shared__ __align__(16) float wpR[HH];
    __shared__ __align__(16) float ebL[HH];
    __shared__ __align__(16) float gbL[HH];
    __shared__ __align__(16) float g2L[HH];
    __shared__ __align__(16) float ewpart[TJ][12];   // transposed, rows 48B
    __shared__ float ewG[TJ];
    __shared__ float vpart[TJ][9];
    __shared__ float vbuf[TJ * 3];

    const int t = threadIdx.x;
    const int i = blockIdx.x >> 1;       // row
    const int z = blockIdx.x & 1;        // j-half
    const int jbase = z * JB;

    const float pxi = pos[i * 3 + 0];
    const float pyi = pos[i * 3 + 1];
    const float pzi = pos[i * 3 + 2];

    // ---- geometry + row staging (once per block, own j-half only) ----
    {
        if (t < JB) {
            int j = jbase + t;
            float rx = pxi - pos[j * 3 + 0];
            float ry = pyi - pos[j * 3 + 1];
            float rz = pzi - pos[j * 3 + 2];
            float d = sqrtf(rx * rx + ry * ry + rz * rz);
            distL[t] = fmaxf(d, 1e-8f);
            pmvL[t] = (pm[i * NN + j] != 0) ? 1.0f : 0.0f;
        }
        if (t < HH) {
            baseI[t] = AiP[i * HH + t];
            wdR[t] = eW1[256 * HH + t];
            wpR[t] = eW1[261 * HH + t];
            ebL[t] = eb2[t];
            gbL[t] = gb1[t];
            g2L[t] = gW2[t];
        }
    }

    // ---- wave / lane decomposition ----
    const int w = t >> 6, l = t & 63;
    const int lr = l & 15;               // j within n-tile / weight col (h)
    const int lg = l >> 4;               // k-group / h-quad group
    const int colxor = lr << 4;          // full 16-slot swizzle
    const int aoff0 = lr * 256 + ((  0 + lg * 16) ^ colxor);
    const int aoff1 = lr * 256 + (( 64 + lg * 16) ^ colxor);
    const int aoff2 = lr * 256 + ((128 + lg * 16) ^ colxor);
    const int aoff3 = lr * 256 + ((192 + lg * 16) ^ colxor);
    const int ewr0 = lr * 256 + ((w * 32 + lg * 8) ^ colxor);
    const int hq = w * 16 + lg * 4;      // this lane's 4 h-rows base

    // ---- A-fragments (transposed weights), block-invariant, remat-proof ----
    auto loadA = [&](const float* __restrict__ W, int kc) -> bf16x8 {
        U8 tmp;
        int col = w * 16 + lr;
#pragma unroll
        for (int e = 0; e < 8; ++e)
            tmp.h[e] = (__bf16)W[(kc * 32 + lg * 8 + e) * HH + col];
        asm volatile("" : "+v"(tmp.u.x), "+v"(tmp.u.y),
                          "+v"(tmp.u.z), "+v"(tmp.u.w));
        return tmp.b;
    };
    const bf16x8 Wf0 = loadA(eW2, 0), Wf1 = loadA(eW2, 1),
                 Wf2 = loadA(eW2, 2), Wf3 = loadA(eW2, 3);
    const bf16x8 Gf0 = loadA(gW1, 0), Gf1 = loadA(gW1, 1),
                 Gf2 = loadA(gW1, 2), Gf3 = loadA(gW1, 3);

    const float gb2s = gb2[0];

    // ---- S1-build mapping (rows jj_s and jj_s+32) ----
    const int jj_s = t >> 4;                 // 0..31
    const int h8 = (t & 15) * 8;             // 8-col slice
    const int s1woff = jj_s * 256 + (((t & 15) * 16) ^ ((jj_s & 15) << 4));

    float macc0 = 0.f, macc1 = 0.f, macc2 = 0.f, macc3 = 0.f;
    float vmx = 0.f, vmy = 0.f, vmz = 0.f;   // vector message (8 lanes/wave)

    __syncthreads();   // geometry / staged rows ready

    for (int jt = 0; jt < NTB; ++jt) {
        const int j0l = jt * TJ;             // local j base

        // ---- phase 1: build S1 tile (2 rows/thread), bf16, swizzled ----
        {
            float4 a0 = *(const float4*)&baseI[h8];
            float4 a1 = *(const float4*)&baseI[h8 + 4];
            float4 w0 = *(const float4*)&wdR[h8];
            float4 w1 = *(const float4*)&wdR[h8 + 4];
            float4 p0 = *(const float4*)&wpR[h8];
            float4 p1 = *(const float4*)&wpR[h8 + 4];
#pragma unroll
            for (int rr = 0; rr < 2; ++rr) {
                int jl = j0l + jj_s + rr * 32;
                int j = jbase + jl;
                float4 bj0 = *(const float4*)&AjP[j * HH + h8];
                float4 bj1 = *(const float4*)&AjP[j * HH + h8 + 4];
                float d = distL[jl], pf = pmvL[jl];
                U8 pk;
                pk.h[0] = (__bf16)fast_silu(a0.x + bj0.x + d * w0.x + pf * p0.x);
                pk.h[1] = (__bf16)fast_silu(a0.y + bj0.y + d * w0.y + pf * p0.y);
                pk.h[2] = (__bf16)fast_silu(a0.z + bj0.z + d * w0.z + pf * p0.z);
                pk.h[3] = (__bf16)fast_silu(a0.w + bj0.w + d * w0.w + pf * p0.w);
                pk.h[4] = (__bf16)fast_silu(a1.x + bj1.x + d * w1.x + pf * p1.x);
                pk.h[5] = (__bf16)fast_silu(a1.y + bj1.y + d * w1.y + pf * p1.y);
                pk.h[6] = (__bf16)fast_silu(a1.z + bj1.z + d * w1.z + pf * p1.z);
                pk.h[7] = (__bf16)fast_silu(a1.w + bj1.w + d * w1.w + pf * p1.w);
                *(uint4*)((char*)S1 + s1woff + rr * 8192) = pk.u;
            }
        }
        __syncthreads();   // b1: S1 ready; prev tile's vpart/ewG fenced

        // ---- deferred vector-message for previous tile (dir recomputed) ----
        if (jt > 0 && l < 8) {
            int jj = w * 8 + l;
            int jpl = j0l - TJ + jj;
            int jp = jbase + jpl;
            float s = vpart[jj][0] + vpart[jj][1] + vpart[jj][2] + vpart[jj][3]
                    + vpart[jj][4] + vpart[jj][5] + vpart[jj][6] + vpart[jj][7];
            float vg = (s + gb2s) * ewG[jj];
            float rx = pxi - pos[jp * 3 + 0];
            float ry = pyi - pos[jp * 3 + 1];
            float rz = pzi - pos[jp * 3 + 2];
            float inv = 1.0f / distL[jpl];
            vmx = fmaf(vg, rx * inv, vmx);
            vmy = fmaf(vg, ry * inv, vmy);
            vmz = fmaf(vg, rz * inv, vmz);
        }

        // ---- phase 2: GEMM1 -> EH^T, 4 n-tiles (j = lr,16+lr,32+lr,48+lr)
        f32x4 acc0, acc1, acc2, acc3;
        {
            float4 eb4 = *(const float4*)&ebL[hq];
            acc0[0] = eb4.x; acc0[1] = eb4.y; acc0[2] = eb4.z; acc0[3] = eb4.w;
            acc1 = acc0; acc2 = acc0; acc3 = acc0;
        }
        {
            bf16x8 b;
            b = ldfrag(S1, aoff0);         acc0 = MFMA(Wf0, b, acc0);
            b = ldfrag(S1, aoff0 + 4096);  acc1 = MFMA(Wf0, b, acc1);
            b = ldfrag(S1, aoff0 + 8192);  acc2 = MFMA(Wf0, b, acc2);
            b = ldfrag(S1, aoff0 + 12288); acc3 = MFMA(Wf0, b, acc3);
            b = ldfrag(S1, aoff1);         acc0 = MFMA(Wf1, b, acc0);
            b = ldfrag(S1, aoff1 + 4096);  acc1 = MFMA(Wf1, b, acc1);
            b = ldfrag(S1, aoff1 + 8192);  acc2 = MFMA(Wf1, b, acc2);
            b = ldfrag(S1, aoff1 + 12288); acc3 = MFMA(Wf1, b, acc3);
            b = ldfrag(S1, aoff2);         acc0 = MFMA(Wf2, b, acc0);
            b = ldfrag(S1, aoff2 + 4096);  acc1 = MFMA(Wf2, b, acc1);
            b = ldfrag(S1, aoff2 + 8192);  acc2 = MFMA(Wf2, b, acc2);
            b = ldfrag(S1, aoff2 + 12288); acc3 = MFMA(Wf2, b, acc3);
            b = ldfrag(S1, aoff3);         acc0 = MFMA(Wf3, b, acc0);
            b = ldfrag(S1, aoff3 + 4096);  acc1 = MFMA(Wf3, b, acc1);
            b = ldfrag(S1, aoff3 + 8192);  acc2 = MFMA(Wf3, b, acc2);
            b = ldfrag(S1, aoff3 + 12288); acc3 = MFMA(Wf3, b, acc3);
        }
        // ew partial row-sums: per-lane 4-h sum + 2 shfls (transposed store)
        {
            float s0 = acc0[0] + acc0[1] + acc0[2] + acc0[3];
            float s1 = acc1[0] + acc1[1] + acc1[2] + acc1[3];
            float s2 = acc2[0] + acc2[1] + acc2[2] + acc2[3];
            float s3 = acc3[0] + acc3[1] + acc3[2] + acc3[3];
            s0 += __shfl_xor(s0, 16); s0 += __shfl_xor(s0, 32);
            s1 += __shfl_xor(s1, 16); s1 += __shfl_xor(s1, 32);
            s2 += __shfl_xor(s2, 16); s2 += __shfl_xor(s2, 32);
            s3 += __shfl_xor(s3, 16); s3 += __shfl_xor(s3, 32);
            if (l < 16) {
                ewpart[l][w]      = s0;
                ewpart[16 + l][w] = s1;
                ewpart[32 + l][w] = s2;
                ewpart[48 + l][w] = s3;
            }
        }
        // packed EH writes (4 h-contiguous bf16 per n-tile)
        {
            U4 p0, p1, p2, p3;
            p0.h[0] = (__bf16)acc0[0]; p0.h[1] = (__bf16)acc0[1];
            p0.h[2] = (__bf16)acc0[2]; p0.h[3] = (__bf16)acc0[3];
            p1.h[0] = (__bf16)acc1[0]; p1.h[1] = (__bf16)acc1[1];
            p1.h[2] = (__bf16)acc1[2]; p1.h[3] = (__bf16)acc1[3];
            p2.h[0] = (__bf16)acc2[0]; p2.h[1] = (__bf16)acc2[1];
            p2.h[2] = (__bf16)acc2[2]; p2.h[3] = (__bf16)acc2[3];
            p3.h[0] = (__bf16)acc3[0]; p3.h[1] = (__bf16)acc3[1];
            p3.h[2] = (__bf16)acc3[2]; p3.h[3] = (__bf16)acc3[3];
            *(uint2*)((char*)EH + ewr0)          = p0.u2;
            *(uint2*)((char*)EH + ewr0 + 4096)   = p1.u2;
            *(uint2*)((char*)EH + ewr0 + 8192)   = p2.u2;
            *(uint2*)((char*)EH + ewr0 + 12288)  = p3.u2;
        }
        __syncthreads();   // b2: EH + ewpart ready

        // ---- phase 3a: redundant per-lane ew (vectorized float4 reads) ----
        float ew0, ew1, ew2, ew3;
        {
            float4 eA, eB;
            eA = *(const float4*)&ewpart[lr][0];
            eB = *(const float4*)&ewpart[lr][4];
            float s0 = (eA.x + eA.y + eA.z + eA.w) + (eB.x + eB.y + eB.z + eB.w);
            eA = *(const float4*)&ewpart[16 + lr][0];
            eB = *(const float4*)&ewpart[16 + lr][4];
            float s1 = (eA.x + eA.y + eA.z + eA.w) + (eB.x + eB.y + eB.z + eB.w);
            eA = *(const float4*)&ewpart[32 + lr][0];
            eB = *(const float4*)&ewpart[32 + lr][4];
            float s2 = (eA.x + eA.y + eA.z + eA.w) + (eB.x + eB.y + eB.z + eB.w);
            eA = *(const float4*)&ewpart[48 + lr][0];
            eB = *(const float4*)&ewpart[48 + lr][4];
            float s3 = (eA.x + eA.y + eA.z + eA.w) + (eB.x + eB.y + eB.z + eB.w);
            ew0 = fast_sig(s0 * (1.0f / HH)) * pmvL[j0l + lr];
            ew1 = fast_sig(s1 * (1.0f / HH)) * pmvL[j0l + 16 + lr];
            ew2 = fast_sig(s2 * (1.0f / HH)) * pmvL[j0l + 32 + lr];
            ew3 = fast_sig(s3 * (1.0f / HH)) * pmvL[j0l + 48 + lr];
        }
        // unique writers: wave 2*nt+(lr>>3), lane lg==0 writes j = nt*16+lr
        if (lg == 0 && (lr >> 3) == (w & 1)) {
            int nt = w >> 1;
            int jj = nt * 16 + lr;
            float ewv = (nt == 0) ? ew0 : (nt == 1) ? ew1 : (nt == 2) ? ew2 : ew3;
            out_ew[i * NN + jbase + j0l + jj] = ewv;
            ewG[jj] = ewv;
        }
        // ---- phase 3b: message acc FIRST (frees acc before GEMM2) ----
        macc0 += ew0 * acc0[0] + ew1 * acc1[0] + ew2 * acc2[0] + ew3 * acc3[0];
        macc1 += ew0 * acc0[1] + ew1 * acc1[1] + ew2 * acc2[1] + ew3 * acc3[1];
        macc2 += ew0 * acc0[2] + ew1 * acc1[2] + ew2 * acc2[2] + ew3 * acc3[2];
        macc3 += ew0 * acc0[3] + ew1 * acc1[3] + ew2 * acc2[3] + ew3 * acc3[3];

        // ---- phase 3c: GEMM2 -> G^T ----
        f32x4 g0, g1, g2, g3;
        {
            float4 gb4 = *(const float4*)&gbL[hq];
            g0[0] = gb4.x; g0[1] = gb4.y; g0[2] = gb4.z; g0[3] = gb4.w;
            g1 = g0; g2 = g0; g3 = g0;
        }
        {
            bf16x8 b;
            b = ldfrag(EH, aoff0);         g0 = MFMA(Gf0, b, g0);
            b = ldfrag(EH, aoff0 + 4096);  g1 = MFMA(Gf0, b, g1);
            b = ldfrag(EH, aoff0 + 8192);  g2 = MFMA(Gf0, b, g2);
            b = ldfrag(EH, aoff0 + 12288); g3 = MFMA(Gf0, b, g3);
            b = ldfrag(EH, aoff1);         g0 = MFMA(Gf1, b, g0);
            b = ldfrag(EH, aoff1 + 4096);  g1 = MFMA(Gf1, b, g1);
            b = ldfrag(EH, aoff1 + 8192);  g2 = MFMA(Gf1, b, g2);
            b = ldfrag(EH, aoff1 + 12288); g3 = MFMA(Gf1, b, g3);
            b = ldfrag(EH, aoff2);         g0 = MFMA(Gf2, b, g0);
            b = ldfrag(EH, aoff2 + 4096);  g1 = MFMA(Gf2, b, g1);
            b = ldfrag(EH, aoff2 + 8192);  g2 = MFMA(Gf2, b, g2);
            b = ldfrag(EH, aoff2 + 12288); g3 = MFMA(Gf2, b, g3);
            b = ldfrag(EH, aoff3);         g0 = MFMA(Gf3, b, g0);
            b = ldfrag(EH, aoff3 + 4096);  g1 = MFMA(Gf3, b, g1);
            b = ldfrag(EH, aoff3 + 8192);  g2 = MFMA(Gf3, b, g2);
            b = ldfrag(EH, aoff3 + 12288); g3 = MFMA(Gf3, b, g3);
        }
        // gate partials: per-lane silu-dot + 2 shfls, per n-tile
        {
            float4 g2v = *(const float4*)&g2L[hq];
            float v0 = fast_silu(g0[0]) * g2v.x + fast_silu(g0[1]) * g2v.y
                     + fast_silu(g0[2]) * g2v.z + fast_silu(g0[3]) * g2v.w;
            float v1 = fast_silu(g1[0]) * g2v.x + fast_silu(g1[1]) * g2v.y
                     + fast_silu(g1[2]) * g2v.z + fast_silu(g1[3]) * g2v.w;
            float v2 = fast_silu(g2[0]) * g2v.x + fast_silu(g2[1]) * g2v.y
                     + fast_silu(g2[2]) * g2v.z + fast_silu(g2[3]) * g2v.w;
            float v3 = fast_silu(g3[0]) * g2v.x + fast_silu(g3[1]) * g2v.y
                     + fast_silu(g3[2]) * g2v.z + fast_silu(g3[3]) * g2v.w;
            v0 += __shfl_xor(v0, 16); v0 += __shfl_xor(v0, 32);
            v1 += __shfl_xor(v1, 16); v1 += __shfl_xor(v1, 32);
            v2 += __shfl_xor(v2, 16); v2 += __shfl_xor(v2, 32);
            v3 += __shfl_xor(v3, 16); v3 += __shfl_xor(v3, 32);
            if (l < 16) {
                vpart[l][w]      = v0;
                vpart[16 + l][w] = v1;
                vpart[32 + l][w] = v2;
                vpart[48 + l][w] = v3;
            }
        }
        // (no 3rd barrier: vpart/ewG consumed next tile after b1)
    }

    // ---- final deferred vector-message (last tile, dir recomputed) ----
    __syncthreads();
    if (l < 8) {
        int jj = w * 8 + l;
        int jpl = (NTB - 1) * TJ + jj;
        int jp = jbase + jpl;
        float s = vpart[jj][0] + vpart[jj][1] + vpart[jj][2] + vpart[jj][3]
                + vpart[jj][4] + vpart[jj][5] + vpart[jj][6] + vpart[jj][7];
        float vg = (s + gb2s) * ewG[jj];
        float rx = pxi - pos[jp * 3 + 0];
        float ry = pyi - pos[jp * 3 + 1];
        float rz = pzi - pos[jp * 3 + 2];
        float inv = 1.0f / distL[jpl];
        vmx = fmaf(vg, rx * inv, vmx);
        vmy = fmaf(vg, ry * inv, vmy);
        vmz = fmaf(vg, rz * inv, vmz);
        vbuf[jj * 3 + 0] = vmx;
        vbuf[jj * 3 + 1] = vmy;
        vbuf[jj * 3 + 2] = vmz;
    }
    // message finalize: reduce over the 16 j-lanes, write partial to ws
    macc0 += __shfl_xor(macc0, 1); macc0 += __shfl_xor(macc0, 2);
    macc0 += __shfl_xor(macc0, 4); macc0 += __shfl_xor(macc0, 8);
    macc1 += __shfl_xor(macc1, 1); macc1 += __shfl_xor(macc1, 2);
    macc1 += __shfl_xor(macc1, 4); macc1 += __shfl_xor(macc1, 8);
    macc2 += __shfl_xor(macc2, 1); macc2 += __shfl_xor(macc2, 2);
    macc2 += __shfl_xor(macc2, 4); macc2 += __shfl_xor(macc2, 8);
    macc3 += __shfl_xor(macc3, 1); macc3 += __shfl_xor(macc3, 2);
    macc3 += __shfl_xor(macc3, 4); macc3 += __shfl_xor(macc3, 8);
    if (lr == 0) {
        *(float4*)&mpartW[blockIdx.x * HH + hq] =
            make_float4(macc0, macc1, macc2, macc3);
    }
    __syncthreads();   // vbuf ready
    if (t < 3) {
        float v = 0.f;
        for (int g = 0; g < TJ; ++g) v += vbuf[g * 3 + t];
        vmW[blockIdx.x * 3 + t] = v;
    }
}

// ---------------- K3: epilogue (combine + scalar MLP + LN + vec) ----------
__global__ void __launch_bounds__(HH)
epilogue_kernel(const float* __restrict__ nf, const float* __restrict__ vf,
                const float* __restrict__ sW1, const float* __restrict__ sb1,
                const float* __restrict__ sW2, const float* __restrict__ sb2,
                const float* __restrict__ ln_g, const float* __restrict__ ln_b,
                const float* __restrict__ mpartW, const float* __restrict__ vmW,
                float* __restrict__ out_scalar, float* __restrict__ out_vec) {
    __shared__ float suin[2 * HH];
    __shared__ float hbuf[HH];
    __shared__ float red2[4];
    const int i = blockIdx.x;
    const int t = threadIdx.x;

    suin[t] = nf[i * HH + t];
    suin[HH + t] = mpartW[(2 * i) * HH + t] + mpartW[(2 * i + 1) * HH + t];
    __syncthreads();
    float a = sb1[t];
    for (int k = 0; k < 2 * HH; ++k) a = fmaf(suin[k], sW1[k * HH + t], a);
    hbuf[t] = fast_silu(a);
    __syncthreads();
    float a2 = sb2[t];
    for (int k = 0; k < HH; ++k) a2 = fmaf(hbuf[k], sW2[k * HH + t], a2);
    float x = nf[i * HH + t] + a2;
    float sx = x, sq = x * x;
#pragma unroll
    for (int msk = 1; msk <= 32; msk <<= 1) {
        sx += __shfl_xor(sx, msk);
        sq += __shfl_xor(sq, msk);
    }
    if (t == 0)  { red2[0] = sx; red2[1] = sq; }
    if (t == 64) { red2[2] = sx; red2[3] = sq; }
    __syncthreads();
    float mean = (red2[0] + red2[2]) * (1.0f / HH);
    float var  = (red2[1] + red2[3]) * (1.0f / HH) - mean * mean;
    out_scalar[i * HH + t] =
        (x - mean) * rsqrtf(var + 1e-5f) * ln_g[t] + ln_b[t];
    if (t < 3) {
        out_vec[i * 3 + t] = vf[i * 3 + t] + vmW[(2 * i) * 3 + t]
                           + vmW[(2 * i + 1) * 3 + t];
    }
}

extern "C" void kernel_launch(void* const* d_in, const int* in_sizes, int n_in,
                              void* d_out, int out_size, void* d_ws, size_t ws_size,
                              hipStream_t stream) {
    const float* nf   = (const float*)d_in[0];
    const float* vf   = (const float*)d_in[1];
    const float* pos  = (const float*)d_in[2];
    const int*   pm   = (const int*)d_in[3];
    const float* cons = (const float*)d_in[4];
    const float* memb = (const float*)d_in[5];
    const float* cata = (const float*)d_in[6];
    const float* eW1  = (const float*)d_in[7];
    const float* eb1  = (const float*)d_in[8];
    const float* eW2  = (const float*)d_in[9];
    const float* eb2  = (const float*)d_in[10];
    const float* sW1  = (const float*)d_in[11];
    const float* sb1  = (const float*)d_in[12];
    const float* sW2  = (const float*)d_in[13];
    const float* sb2  = (const float*)d_in[14];
    const float* gW1  = (const float*)d_in[15];
    const float* gb1  = (const float*)d_in[16];
    const float* gW2  = (const float*)d_in[17];
    const float* gb2  = (const float*)d_in[18];
    const float* lng  = (const float*)d_in[19];
    const float* lnb  = (const float*)d_in[20];

    float* out = (float*)d_out;
    float* out_scalar = out;                     // [768*128]
    float* out_vec    = out + NN * HH;           // [768*3]
    float* out_ew     = out + NN * HH + NN * 3;  // [768*768]

    float* AiP    = (float*)d_ws;                // [768*128]
    float* AjP    = AiP + NN * HH;               // [768*128]
    float* mpartW = AjP + NN * HH;               // [1536*128]
    float* vmW    = mpartW + 2 * NN * HH;        // [1536*3]

    precompute_proj<<<NN, HH, 0, stream>>>(nf, cons, memb, cata, eW1, eb1, AiP, AjP);

    main_kernel<<<2 * NN, THREADS, 0, stream>>>(
        pos, pm, eW1, eW2, eb2, gW1, gb1, gW2, gb2,
        AiP, AjP, mpartW, vmW, out_ew);

    epilogue_kernel<<<NN, HH, 0, stream>>>(
        nf, vf, sW1, sb1, sW2, sb2, lng, lnb, mpartW, vmW,
        out_scalar, out_vec);
}

// Round 22
// 103.774 us; speedup vs baseline: 1.5042x; 1.0143x over previous
//
#include <hip/hip_runtime.h>

#define NN 768
#define HH 128
#define TJ 64
#define NTB 6                 // j-tiles per block (half row)
#define JB  (NTB * TJ)        // 384 j's per block
#define THREADS 512

typedef __bf16 bf16x8 __attribute__((ext_vector_type(8)));
typedef float f32x4 __attribute__((ext_vector_type(4)));

union U8 { __bf16 h[8]; unsigned short s[8]; uint4 u; bf16x8 b; };
union U4 { __bf16 h[4]; uint2 u2; };

__device__ __forceinline__ float fast_sig(float x) {
    return __builtin_amdgcn_rcpf(1.0f + __expf(-x));
}
__device__ __forceinline__ float fast_silu(float x) { return x * fast_sig(x); }

__device__ __forceinline__ f32x4 MFMA(bf16x8 a, bf16x8 b, f32x4 c) {
    return __builtin_amdgcn_mfma_f32_16x16x32_bf16(a, b, c, 0, 0, 0);
}

__device__ __forceinline__ bf16x8 ldfrag(const unsigned short* buf, int off) {
    U8 r;
    r.u = *(const uint4*)((const char*)buf + off);
    return r.b;
}

// ---------------- K1: per-node projections AiP/AjP ----------------
__global__ void precompute_proj(const float* __restrict__ nf,
                                const float* __restrict__ cons,
                                const float* __restrict__ memb,
                                const float* __restrict__ cata,
                                const float* __restrict__ eW1,
                                const float* __restrict__ eb1,
                                float* __restrict__ AiP,
                                float* __restrict__ AjP) {
    __shared__ float row[HH];
    int i = blockIdx.x;
    int h = threadIdx.x;
    row[h] = nf[i * HH + h];
    __syncthreads();
    float ci = cons[i], mi = memb[i], ti = cata[i];
    float ai = eb1[h] + ci * eW1[257 * HH + h] + mi * eW1[259 * HH + h];
    float aj = ci * eW1[258 * HH + h] + ti * eW1[260 * HH + h];
    for (int k = 0; k < HH; ++k) {
        float x = row[k];
        ai = fmaf(x, eW1[k * HH + h], ai);
        aj = fmaf(x, eW1[(HH + k) * HH + h], aj);
    }
    AiP[i * HH + h] = ai;
    AjP[i * HH + h] = aj;
}

// ---------------- K2: main kernel — HALF ROW per block ----------------
// Round-19 structure (proven 105 us) + T5: s_setprio(1) around both MFMA
// clusters. 2 independent blocks/CU -> co-resident waves sit in different
// phases (BUILD-VALU vs GEMM-MFMA); setprio lets MFMA-entering waves win
// issue arbitration (m191 regime, +4-7% there).
__global__ void __launch_bounds__(THREADS, 4)
main_kernel(const float* __restrict__ pos, const int* __restrict__ pm,
            const float* __restrict__ eW1, const float* __restrict__ eW2,
            const float* __restrict__ eb2,
            const float* __restrict__ gW1, const float* __restrict__ gb1,
            const float* __restrict__ gW2, const float* __restrict__ gb2,
            const float* __restrict__ AiP, const float* __restrict__ AjP,
            float* __restrict__ mpartW, float* __restrict__ vmW,
            float* __restrict__ out_ew) {
    // ---- LDS (~46 KB) ----
    __shared__ __align__(16) unsigned short S1[TJ * HH];   // 16 KB, swizzled
    __shared__ __align__(16) unsigned short EH[TJ * HH];   // 16 KB, swizzled
    __shared__ float distL[JB];
    __shared__ float pmvL[JB];
    __shared__ __align__(16) float baseI[HH];
    __shared__ __align__(16) float wdR[HH];
    __shared__ __align__(16) float wpR[HH];
    __shared__ __align__(16) float ebL[HH];
    __shared__ __align__(16) float gbL[HH];
    __shared__ __align__(16) float g2L[HH];
    __shared__ __align__(16) float ewpart[TJ][12];   // transposed, rows 48B
    __shared__ float ewG[TJ];
    __shared__ float vpart[TJ][9];
    __shared__ float vbuf[TJ * 3];

    const int t = threadIdx.x;
    const int i = blockIdx.x >> 1;       // row
    const int z = blockIdx.x & 1;        // j-half
    const int jbase = z * JB;

    const float pxi = pos[i * 3 + 0];
    const float pyi = pos[i * 3 + 1];
    const float pzi = pos[i * 3 + 2];

    // ---- geometry + row staging (once per block, own j-half only) ----
    {
        if (t < JB) {
            int j = jbase + t;
            float rx = pxi - pos[j * 3 + 0];
            float ry = pyi - pos[j * 3 + 1];
            float rz = pzi - pos[j * 3 + 2];
            float d = sqrtf(rx * rx + ry * ry + rz * rz);
            distL[t] = fmaxf(d, 1e-8f);
            pmvL[t] = (pm[i * NN + j] != 0) ? 1.0f : 0.0f;
        }
        if (t < HH) {
            baseI[t] = AiP[i * HH + t];
            wdR[t] = eW1[256 * HH + t];
            wpR[t] = eW1[261 * HH + t];
            ebL[t] = eb2[t];
            gbL[t] = gb1[t];
            g2L[t] = gW2[t];
        }
    }

    // ---- wave / lane decomposition ----
    const int w = t >> 6, l = t & 63;
    const int lr = l & 15;               // j within n-tile / weight col (h)
    const int lg = l >> 4;               // k-group / h-quad group
    const int colxor = lr << 4;          // full 16-slot swizzle
    const int aoff0 = lr * 256 + ((  0 + lg * 16) ^ colxor);
    const int aoff1 = lr * 256 + (( 64 + lg * 16) ^ colxor);
    const int aoff2 = lr * 256 + ((128 + lg * 16) ^ colxor);
    const int aoff3 = lr * 256 + ((192 + lg * 16) ^ colxor);
    const int ewr0 = lr * 256 + ((w * 32 + lg * 8) ^ colxor);
    const int hq = w * 16 + lg * 4;      // this lane's 4 h-rows base

    // ---- A-fragments (transposed weights), block-invariant, remat-proof ----
    auto loadA = [&](const float* __restrict__ W, int kc) -> bf16x8 {
        U8 tmp;
        int col = w * 16 + lr;
#pragma unroll
        for (int e = 0; e < 8; ++e)
            tmp.h[e] = (__bf16)W[(kc * 32 + lg * 8 + e) * HH + col];
        asm volatile("" : "+v"(tmp.u.x), "+v"(tmp.u.y),
                          "+v"(tmp.u.z), "+v"(tmp.u.w));
        return tmp.b;
    };
    const bf16x8 Wf0 = loadA(eW2, 0), Wf1 = loadA(eW2, 1),
                 Wf2 = loadA(eW2, 2), Wf3 = loadA(eW2, 3);
    const bf16x8 Gf0 = loadA(gW1, 0), Gf1 = loadA(gW1, 1),
                 Gf2 = loadA(gW1, 2), Gf3 = loadA(gW1, 3);

    const float gb2s = gb2[0];

    // ---- S1-build mapping (rows jj_s and jj_s+32) ----
    const int jj_s = t >> 4;                 // 0..31
    const int h8 = (t & 15) * 8;             // 8-col slice
    const int s1woff = jj_s * 256 + (((t & 15) * 16) ^ ((jj_s & 15) << 4));

    float macc0 = 0.f, macc1 = 0.f, macc2 = 0.f, macc3 = 0.f;
    float vmx = 0.f, vmy = 0.f, vmz = 0.f;   // vector message (8 lanes/wave)

    __syncthreads();   // geometry / staged rows ready

    for (int jt = 0; jt < NTB; ++jt) {
        const int j0l = jt * TJ;             // local j base

        // ---- phase 1: build S1 tile (2 rows/thread), bf16, swizzled ----
        {
            float4 a0 = *(const float4*)&baseI[h8];
            float4 a1 = *(const float4*)&baseI[h8 + 4];
            float4 w0 = *(const float4*)&wdR[h8];
            float4 w1 = *(const float4*)&wdR[h8 + 4];
            float4 p0 = *(const float4*)&wpR[h8];
            float4 p1 = *(const float4*)&wpR[h8 + 4];
#pragma unroll
            for (int rr = 0; rr < 2; ++rr) {
                int jl = j0l + jj_s + rr * 32;
                int j = jbase + jl;
                float4 bj0 = *(const float4*)&AjP[j * HH + h8];
                float4 bj1 = *(const float4*)&AjP[j * HH + h8 + 4];
                float d = distL[jl], pf = pmvL[jl];
                U8 pk;
                pk.h[0] = (__bf16)fast_silu(a0.x + bj0.x + d * w0.x + pf * p0.x);
                pk.h[1] = (__bf16)fast_silu(a0.y + bj0.y + d * w0.y + pf * p0.y);
                pk.h[2] = (__bf16)fast_silu(a0.z + bj0.z + d * w0.z + pf * p0.z);
                pk.h[3] = (__bf16)fast_silu(a0.w + bj0.w + d * w0.w + pf * p0.w);
                pk.h[4] = (__bf16)fast_silu(a1.x + bj1.x + d * w1.x + pf * p1.x);
                pk.h[5] = (__bf16)fast_silu(a1.y + bj1.y + d * w1.y + pf * p1.y);
                pk.h[6] = (__bf16)fast_silu(a1.z + bj1.z + d * w1.z + pf * p1.z);
                pk.h[7] = (__bf16)fast_silu(a1.w + bj1.w + d * w1.w + pf * p1.w);
                *(uint4*)((char*)S1 + s1woff + rr * 8192) = pk.u;
            }
        }
        __syncthreads();   // b1: S1 ready; prev tile's vpart/ewG fenced

        // ---- deferred vector-message for previous tile (dir recomputed) ----
        if (jt > 0 && l < 8) {
            int jj = w * 8 + l;
            int jpl = j0l - TJ + jj;
            int jp = jbase + jpl;
            float s = vpart[jj][0] + vpart[jj][1] + vpart[jj][2] + vpart[jj][3]
                    + vpart[jj][4] + vpart[jj][5] + vpart[jj][6] + vpart[jj][7];
            float vg = (s + gb2s) * ewG[jj];
            float rx = pxi - pos[jp * 3 + 0];
            float ry = pyi - pos[jp * 3 + 1];
            float rz = pzi - pos[jp * 3 + 2];
            float inv = 1.0f / distL[jpl];
            vmx = fmaf(vg, rx * inv, vmx);
            vmy = fmaf(vg, ry * inv, vmy);
            vmz = fmaf(vg, rz * inv, vmz);
        }

        // ---- phase 2: GEMM1 -> EH^T, 4 n-tiles (j = lr,16+lr,32+lr,48+lr)
        f32x4 acc0, acc1, acc2, acc3;
        {
            float4 eb4 = *(const float4*)&ebL[hq];
            acc0[0] = eb4.x; acc0[1] = eb4.y; acc0[2] = eb4.z; acc0[3] = eb4.w;
            acc1 = acc0; acc2 = acc0; acc3 = acc0;
        }
        __builtin_amdgcn_s_setprio(1);
        {
            bf16x8 b;
            b = ldfrag(S1, aoff0);         acc0 = MFMA(Wf0, b, acc0);
            b = ldfrag(S1, aoff0 + 4096);  acc1 = MFMA(Wf0, b, acc1);
            b = ldfrag(S1, aoff0 + 8192);  acc2 = MFMA(Wf0, b, acc2);
            b = ldfrag(S1, aoff0 + 12288); acc3 = MFMA(Wf0, b, acc3);
            b = ldfrag(S1, aoff1);         acc0 = MFMA(Wf1, b, acc0);
            b = ldfrag(S1, aoff1 + 4096);  acc1 = MFMA(Wf1, b, acc1);
            b = ldfrag(S1, aoff1 + 8192);  acc2 = MFMA(Wf1, b, acc2);
            b = ldfrag(S1, aoff1 + 12288); acc3 = MFMA(Wf1, b, acc3);
            b = ldfrag(S1, aoff2);         acc0 = MFMA(Wf2, b, acc0);
            b = ldfrag(S1, aoff2 + 4096);  acc1 = MFMA(Wf2, b, acc1);
            b = ldfrag(S1, aoff2 + 8192);  acc2 = MFMA(Wf2, b, acc2);
            b = ldfrag(S1, aoff2 + 12288); acc3 = MFMA(Wf2, b, acc3);
            b = ldfrag(S1, aoff3);         acc0 = MFMA(Wf3, b, acc0);
            b = ldfrag(S1, aoff3 + 4096);  acc1 = MFMA(Wf3, b, acc1);
            b = ldfrag(S1, aoff3 + 8192);  acc2 = MFMA(Wf3, b, acc2);
            b = ldfrag(S1, aoff3 + 12288); acc3 = MFMA(Wf3, b, acc3);
        }
        __builtin_amdgcn_s_setprio(0);
        // ew partial row-sums: per-lane 4-h sum + 2 shfls (transposed store)
        {
            float s0 = acc0[0] + acc0[1] + acc0[2] + acc0[3];
            float s1 = acc1[0] + acc1[1] + acc1[2] + acc1[3];
            float s2 = acc2[0] + acc2[1] + acc2[2] + acc2[3];
            float s3 = acc3[0] + acc3[1] + acc3[2] + acc3[3];
            s0 += __shfl_xor(s0, 16); s0 += __shfl_xor(s0, 32);
            s1 += __shfl_xor(s1, 16); s1 += __shfl_xor(s1, 32);
            s2 += __shfl_xor(s2, 16); s2 += __shfl_xor(s2, 32);
            s3 += __shfl_xor(s3, 16); s3 += __shfl_xor(s3, 32);
            if (l < 16) {
                ewpart[l][w]      = s0;
                ewpart[16 + l][w] = s1;
                ewpart[32 + l][w] = s2;
                ewpart[48 + l][w] = s3;
            }
        }
        // packed EH writes (4 h-contiguous bf16 per n-tile)
        {
            U4 p0, p1, p2, p3;
            p0.h[0] = (__bf16)acc0[0]; p0.h[1] = (__bf16)acc0[1];
            p0.h[2] = (__bf16)acc0[2]; p0.h[3] = (__bf16)acc0[3];
            p1.h[0] = (__bf16)acc1[0]; p1.h[1] = (__bf16)acc1[1];
            p1.h[2] = (__bf16)acc1[2]; p1.h[3] = (__bf16)acc1[3];
            p2.h[0] = (__bf16)acc2[0]; p2.h[1] = (__bf16)acc2[1];
            p2.h[2] = (__bf16)acc2[2]; p2.h[3] = (__bf16)acc2[3];
            p3.h[0] = (__bf16)acc3[0]; p3.h[1] = (__bf16)acc3[1];
            p3.h[2] = (__bf16)acc3[2]; p3.h[3] = (__bf16)acc3[3];
            *(uint2*)((char*)EH + ewr0)          = p0.u2;
            *(uint2*)((char*)EH + ewr0 + 4096)   = p1.u2;
            *(uint2*)((char*)EH + ewr0 + 8192)   = p2.u2;
            *(uint2*)((char*)EH + ewr0 + 12288)  = p3.u2;
        }
        __syncthreads();   // b2: EH + ewpart ready

        // ---- phase 3a: redundant per-lane ew (vectorized float4 reads) ----
        float ew0, ew1, ew2, ew3;
        {
            float4 eA, eB;
            eA = *(const float4*)&ewpart[lr][0];
            eB = *(const float4*)&ewpart[lr][4];
            float s0 = (eA.x + eA.y + eA.z + eA.w) + (eB.x + eB.y + eB.z + eB.w);
            eA = *(const float4*)&ewpart[16 + lr][0];
            eB = *(const float4*)&ewpart[16 + lr][4];
            float s1 = (eA.x + eA.y + eA.z + eA.w) + (eB.x + eB.y + eB.z + eB.w);
            eA = *(const float4*)&ewpart[32 + lr][0];
            eB = *(const float4*)&ewpart[32 + lr][4];
            float s2 = (eA.x + eA.y + eA.z + eA.w) + (eB.x + eB.y + eB.z + eB.w);
            eA = *(const float4*)&ewpart[48 + lr][0];
            eB = *(const float4*)&ewpart[48 + lr][4];
            float s3 = (eA.x + eA.y + eA.z + eA.w) + (eB.x + eB.y + eB.z + eB.w);
            ew0 = fast_sig(s0 * (1.0f / HH)) * pmvL[j0l + lr];
            ew1 = fast_sig(s1 * (1.0f / HH)) * pmvL[j0l + 16 + lr];
            ew2 = fast_sig(s2 * (1.0f / HH)) * pmvL[j0l + 32 + lr];
            ew3 = fast_sig(s3 * (1.0f / HH)) * pmvL[j0l + 48 + lr];
        }
        // unique writers: wave 2*nt+(lr>>3), lane lg==0 writes j = nt*16+lr
        if (lg == 0 && (lr >> 3) == (w & 1)) {
            int nt = w >> 1;
            int jj = nt * 16 + lr;
            float ewv = (nt == 0) ? ew0 : (nt == 1) ? ew1 : (nt == 2) ? ew2 : ew3;
            out_ew[i * NN + jbase + j0l + jj] = ewv;
            ewG[jj] = ewv;
        }
        // ---- phase 3b: message acc FIRST (frees acc before GEMM2) ----
        macc0 += ew0 * acc0[0] + ew1 * acc1[0] + ew2 * acc2[0] + ew3 * acc3[0];
        macc1 += ew0 * acc0[1] + ew1 * acc1[1] + ew2 * acc2[1] + ew3 * acc3[1];
        macc2 += ew0 * acc0[2] + ew1 * acc1[2] + ew2 * acc2[2] + ew3 * acc3[2];
        macc3 += ew0 * acc0[3] + ew1 * acc1[3] + ew2 * acc2[3] + ew3 * acc3[3];

        // ---- phase 3c: GEMM2 -> G^T ----
        f32x4 g0, g1, g2, g3;
        {
            float4 gb4 = *(const float4*)&gbL[hq];
            g0[0] = gb4.x; g0[1] = gb4.y; g0[2] = gb4.z; g0[3] = gb4.w;
            g1 = g0; g2 = g0; g3 = g0;
        }
        __builtin_amdgcn_s_setprio(1);
        {
            bf16x8 b;
            b = ldfrag(EH, aoff0);         g0 = MFMA(Gf0, b, g0);
            b = ldfrag(EH, aoff0 + 4096);  g1 = MFMA(Gf0, b, g1);
            b = ldfrag(EH, aoff0 + 8192);  g2 = MFMA(Gf0, b, g2);
            b = ldfrag(EH, aoff0 + 12288); g3 = MFMA(Gf0, b, g3);
            b = ldfrag(EH, aoff1);         g0 = MFMA(Gf1, b, g0);
            b = ldfrag(EH, aoff1 + 4096);  g1 = MFMA(Gf1, b, g1);
            b = ldfrag(EH, aoff1 + 8192);  g2 = MFMA(Gf1, b, g2);
            b = ldfrag(EH, aoff1 + 12288); g3 = MFMA(Gf1, b, g3);
            b = ldfrag(EH, aoff2);         g0 = MFMA(Gf2, b, g0);
            b = ldfrag(EH, aoff2 + 4096);  g1 = MFMA(Gf2, b, g1);
            b = ldfrag(EH, aoff2 + 8192);  g2 = MFMA(Gf2, b, g2);
            b = ldfrag(EH, aoff2 + 12288); g3 = MFMA(Gf2, b, g3);
            b = ldfrag(EH, aoff3);         g0 = MFMA(Gf3, b, g0);
            b = ldfrag(EH, aoff3 + 4096);  g1 = MFMA(Gf3, b, g1);
            b = ldfrag(EH, aoff3 + 8192);  g2 = MFMA(Gf3, b, g2);
            b = ldfrag(EH, aoff3 + 12288); g3 = MFMA(Gf3, b, g3);
        }
        __builtin_amdgcn_s_setprio(0);
        // gate partials: per-lane silu-dot + 2 shfls, per n-tile
        {
            float4 g2v = *(const float4*)&g2L[hq];
            float v0 = fast_silu(g0[0]) * g2v.x + fast_silu(g0[1]) * g2v.y
                     + fast_silu(g0[2]) * g2v.z + fast_silu(g0[3]) * g2v.w;
            float v1 = fast_silu(g1[0]) * g2v.x + fast_silu(g1[1]) * g2v.y
                     + fast_silu(g1[2]) * g2v.z + fast_silu(g1[3]) * g2v.w;
            float v2 = fast_silu(g2[0]) * g2v.x + fast_silu(g2[1]) * g2v.y
                     + fast_silu(g2[2]) * g2v.z + fast_silu(g2[3]) * g2v.w;
            float v3 = fast_silu(g3[0]) * g2v.x + fast_silu(g3[1]) * g2v.y
                     + fast_silu(g3[2]) * g2v.z + fast_silu(g3[3]) * g2v.w;
            v0 += __shfl_xor(v0, 16); v0 += __shfl_xor(v0, 32);
            v1 += __shfl_xor(v1, 16); v1 += __shfl_xor(v1, 32);
            v2 += __shfl_xor(v2, 16); v2 += __shfl_xor(v2, 32);
            v3 += __shfl_xor(v3, 16); v3 += __shfl_xor(v3, 32);
            if (l < 16) {
                vpart[l][w]      = v0;
                vpart[16 + l][w] = v1;
                vpart[32 + l][w] = v2;
                vpart[48 + l][w] = v3;
            }
        }
        // (no 3rd barrier: vpart/ewG consumed next tile after b1)
    }

    // ---- final deferred vector-message (last tile, dir recomputed) ----
    __syncthreads();
    if (l < 8) {
        int jj = w * 8 + l;
        int jpl = (NTB - 1) * TJ + jj;
        int jp = jbase + jpl;
        float s = vpart[jj][0] + vpart[jj][1] + vpart[jj][2] + vpart[jj][3]
                + vpart[jj][4] + vpart[jj][5] + vpart[jj][6] + vpart[jj][7];
        float vg = (s + gb2s) * ewG[jj];
        float rx = pxi - pos[jp * 3 + 0];
        float ry = pyi - pos[jp * 3 + 1];
        float rz = pzi - pos[jp * 3 + 2];
        float inv = 1.0f / distL[jpl];
        vmx = fmaf(vg, rx * inv, vmx);
        vmy = fmaf(vg, ry * inv, vmy);
        vmz = fmaf(vg, rz * inv, vmz);
        vbuf[jj * 3 + 0] = vmx;
        vbuf[jj * 3 + 1] = vmy;
        vbuf[jj * 3 + 2] = vmz;
    }
    // message finalize: reduce over the 16 j-lanes, write partial to ws
    macc0 += __shfl_xor(macc0, 1); macc0 += __shfl_xor(macc0, 2);
    macc0 += __shfl_xor(macc0, 4); macc0 += __shfl_xor(macc0, 8);
    macc1 += __shfl_xor(macc1, 1); macc1 += __shfl_xor(macc1, 2);
    macc1 += __shfl_xor(macc1, 4); macc1 += __shfl_xor(macc1, 8);
    macc2 += __shfl_xor(macc2, 1); macc2 += __shfl_xor(macc2, 2);
    macc2 += __shfl_xor(macc2, 4); macc2 += __shfl_xor(macc2, 8);
    macc3 += __shfl_xor(macc3, 1); macc3 += __shfl_xor(macc3, 2);
    macc3 += __shfl_xor(macc3, 4); macc3 += __shfl_xor(macc3, 8);
    if (lr == 0) {
        *(float4*)&mpartW[blockIdx.x * HH + hq] =
            make_float4(macc0, macc1, macc2, macc3);
    }
    __syncthreads();   // vbuf ready
    if (t < 3) {
        float v = 0.f;
        for (int g = 0; g < TJ; ++g) v += vbuf[g * 3 + t];
        vmW[blockIdx.x * 3 + t] = v;
    }
}

// ---------------- K3: epilogue (combine + scalar MLP + LN + vec) ----------
__global__ void __launch_bounds__(HH)
epilogue_kernel(const float* __restrict__ nf, const float* __restrict__ vf,
                const float* __restrict__ sW1, const float* __restrict__ sb1,
                const float* __restrict__ sW2, const float* __restrict__ sb2,
                const float* __restrict__ ln_g, const float* __restrict__ ln_b,
                const float* __restrict__ mpartW, const float* __restrict__ vmW,
                float* __restrict__ out_scalar, float* __restrict__ out_vec) {
    __shared__ float suin[2 * HH];
    __shared__ float hbuf[HH];
    __shared__ float red2[4];
    const int i = blockIdx.x;
    const int t = threadIdx.x;

    suin[t] = nf[i * HH + t];
    suin[HH + t] = mpartW[(2 * i) * HH + t] + mpartW[(2 * i + 1) * HH + t];
    __syncthreads();
    float a = sb1[t];
    for (int k = 0; k < 2 * HH; ++k) a = fmaf(suin[k], sW1[k * HH + t], a);
    hbuf[t] = fast_silu(a);
    __syncthreads();
    float a2 = sb2[t];
    for (int k = 0; k < HH; ++k) a2 = fmaf(hbuf[k], sW2[k * HH + t], a2);
    float x = nf[i * HH + t] + a2;
    float sx = x, sq = x * x;
#pragma unroll
    for (int msk = 1; msk <= 32; msk <<= 1) {
        sx += __shfl_xor(sx, msk);
        sq += __shfl_xor(sq, msk);
    }
    if (t == 0)  { red2[0] = sx; red2[1] = sq; }
    if (t == 64) { red2[2] = sx; red2[3] = sq; }
    __syncthreads();
    float mean = (red2[0] + red2[2]) * (1.0f / HH);
    float var  = (red2[1] + red2[3]) * (1.0f / HH) - mean * mean;
    out_scalar[i * HH + t] =
        (x - mean) * rsqrtf(var + 1e-5f) * ln_g[t] + ln_b[t];
    if (t < 3) {
        out_vec[i * 3 + t] = vf[i * 3 + t] + vmW[(2 * i) * 3 + t]
                           + vmW[(2 * i + 1) * 3 + t];
    }
}

extern "C" void kernel_launch(void* const* d_in, const int* in_sizes, int n_in,
                              void* d_out, int out_size, void* d_ws, size_t ws_size,
                              hipStream_t stream) {
    const float* nf   = (const float*)d_in[0];
    const float* vf   = (const float*)d_in[1];
    const float* pos  = (const float*)d_in[2];
    const int*   pm   = (const int*)d_in[3];
    const float* cons = (const float*)d_in[4];
    const float* memb = (const float*)d_in[5];
    const float* cata = (const float*)d_in[6];
    const float* eW1  = (const float*)d_in[7];
    const float* eb1  = (const float*)d_in[8];
    const float* eW2  = (const float*)d_in[9];
    const float* eb2  = (const float*)d_in[10];
    const float* sW1  = (const float*)d_in[11];
    const float* sb1  = (const float*)d_in[12];
    const float* sW2  = (const float*)d_in[13];
    const float* sb2  = (const float*)d_in[14];
    const float* gW1  = (const float*)d_in[15];
    const float* gb1  = (const float*)d_in[16];
    const float* gW2  = (const float*)d_in[17];
    const float* gb2  = (const float*)d_in[18];
    const float* lng  = (const float*)d_in[19];
    const float* lnb  = (const float*)d_in[20];

    float* out = (float*)d_out;
    float* out_scalar = out;                     // [768*128]
    float* out_vec    = out + NN * HH;           // [768*3]
    float* out_ew     = out + NN * HH + NN * 3;  // [768*768]

    float* AiP    = (float*)d_ws;                // [768*128]
    float* AjP    = AiP + NN * HH;               // [768*128]
    float* mpartW = AjP + NN * HH;               // [1536*128]
    float* vmW    = mpartW + 2 * NN * HH;        // [1536*3]

    precompute_proj<<<NN, HH, 0, stream>>>(nf, cons, memb, cata, eW1, eb1, AiP, AjP);

    main_kernel<<<2 * NN, THREADS, 0, stream>>>(
        pos, pm, eW1, eW2, eb2, gW1, gb1, gW2, gb2,
        AiP, AjP, mpartW, vmW, out_ew);

    epilogue_kernel<<<NN, HH, 0, stream>>>(
        nf, vf, sW1, sb1, sW2, sb2, lng, lnb, mpartW, vmW,
        out_scalar, out_vec);
}